// Round 23
// baseline (2639.184 us; speedup 1.0000x reference)
//
#include <hip/hip_runtime.h>
#include <cstdint>
#include <cstddef>

// ---------------- problem constants ----------------
#define SEQ    512
#define BATCH  128
#define EMB    512
#define HID    1024
#define KTOT   1536   // EMB + HID fused K
#define NOUT   8

// ---------------- decomposition ----------------
// 4 row-groups (32 batch rows) x 64 col-blocks (16 units / 64 gate-cols).
// Block = 256 thr = 4 waves; BALANCED K: every wave 4 x-chunks + 8 h-chunks.
// W in VGPRs (192/lane). Per-wave monotone flags, pipelined sleep-free polls,
// 1 barrier/step, double-buffered pacc. R23: bias folded into kq0 acc-init,
// paired u64 h-stores (half the drain), 2-in-flight flag polling.
#define RG     4
#define NBQ    64            // col-blocks per row-group
#define NBLK   (RG*NBQ)      // 256
#define ROWS   32            // batch rows per block

// balanced fused-K mapping for wave kq, chunk c (compile-time c)
#define KMAP(kq, c) ((c) < 4 ? ((kq)*128 + (c)*32) : (512 + (kq)*256 + ((c)-4)*32))

typedef unsigned short u16;
typedef unsigned int   u32;
typedef unsigned long long u64;
typedef __attribute__((ext_vector_type(8))) __bf16 bf16x8;
typedef __attribute__((ext_vector_type(4))) float  f32x4;
typedef __attribute__((ext_vector_type(4))) float  float4v;
typedef __attribute__((ext_vector_type(4))) u16    u16x4;

// ---------------- workspace layout ----------------
#define OFF_X    0ull
#define SZ_X     ((size_t)SEQ*BATCH*EMB*2)       // 64 MB  bf16 x [S][B][E]
#define OFF_W    (OFF_X + SZ_X)
#define SZ_W     ((size_t)4*HID*KTOT*2)          // 12 MB  bf16 Wp[gc][k], gc=unit*4+q
#define OFF_RING (OFF_W + SZ_W)
#define SZ_RING  ((size_t)(SEQ+1)*BATCH*HID*2)   // 134 MB h ring
#define OFF_FW   (OFF_RING + SZ_RING)
#define SZ_FW    ((size_t)RG*NBQ*4*64)           // 64 KB per-wave flag lines
#define WS_NEED  (OFF_FW + SZ_FW)

// ---------------- helpers ----------------
__device__ inline u16 f2b(float f) {            // f32 -> bf16 RNE
  uint32_t u = __builtin_bit_cast(uint32_t, f);
  u = u + 0x7FFFu + ((u >> 16) & 1u);
  return (u16)(u >> 16);
}
__device__ inline float b2f(u16 u) {
  uint32_t v = ((uint32_t)u) << 16;
  return __builtin_bit_cast(float, v);
}
__device__ inline float sigm(float x) { return 1.0f / (1.0f + __expf(-x)); }
__device__ inline float tanh_(float x) {
  x = fminf(fmaxf(x, -15.f), 15.f);
  float e = __expf(2.f * x);
  return (e - 1.f) / (e + 1.f);
}
__device__ inline f32x4 mfma16(bf16x8 a, bf16x8 b, f32x4 c) {
  return __builtin_amdgcn_mfma_f32_16x16x32_bf16(a, b, c, 0, 0, 0);
}

// ---------------- prep: embedding gather -> bf16 x[t][b][e] ----------------
__global__ void embed_kernel(const int* __restrict__ ids,
                             const float* __restrict__ emb,
                             u16* __restrict__ x) {
  int bid = blockIdx.x;            // t*128 + b
  int t = bid >> 7, b = bid & 127;
  int idx = ids[b * SEQ + t];
  const float4v* src = (const float4v*)(emb + (size_t)idx * EMB);
  float4v v = src[threadIdx.x];
  u16x4 o;
  o.x = f2b(v.x); o.y = f2b(v.y); o.z = f2b(v.z); o.w = f2b(v.w);
  *(u16x4*)(x + (size_t)bid * EMB + threadIdx.x * 4) = o;
}

// ---------------- prep: pack fused W, unit-major: gc=unit*4+q -----------
__global__ void wpack_kernel(const float* __restrict__ Wih,
                             const float* __restrict__ Whh,
                             u16* __restrict__ Wp) {
  int gc = blockIdx.x;             // 0..4095
  int unit = gc >> 2, q = gc & 3;
  int row = q * HID + unit;
  u16* dst = Wp + (size_t)gc * KTOT;
  for (int k = threadIdx.x; k < KTOT; k += 256) {
    float v = (k < EMB) ? Wih[(size_t)row * EMB + k]
                        : Whh[(size_t)row * HID + (k - EMB)];
    dst[k] = f2b(v);
  }
}

// ---------------- persistent LSTM recurrence (balanced, 1-barrier) ---------
__global__ __launch_bounds__(256, 1) void lstm_kernel(
    const u16* __restrict__ x,     // [SEQ][BATCH][EMB] bf16
    const u16* __restrict__ Wp,    // [4096][KTOT] bf16 packed
    const float* __restrict__ bias,// [4*HID] f32 gate-major
    u16* __restrict__ ring,        // [SEQ+1][BATCH][HID]; ring[0]=0
    u32* __restrict__ fw)          // [RG][NBQ][4] per-wave flags (zeroed; monotone)
{
  __shared__ float pacc[2][4][ROWS][68];     // double-buffered partials (70KB)

  const int tid  = threadIdx.x;
  const int bid  = blockIdx.x;
  const int rg   = bid & 3;        // row-group (co-XCD under round-robin)
  const int nb   = bid >> 2;       // col-block 0..63
  const int lane = tid & 63;
  const int kq   = tid >> 6;       // wave = balanced K-slice
  const int l15  = lane & 15;
  const int lhi  = lane >> 4;

  const int arow = rg * ROWS + l15;          // A-fragment base batch row

  // ---- producer flag line of THIS wave ----
  u32* fw_own = &fw[(((size_t)rg * NBQ + nb) * 4 + kq) * 16];
  // wave kq consumes h cols [kq*256, kq*256+256) -> producer blocks
  // cb in [16*kq, 16*kq+16): 64 flags, exactly one per lane.
  const u32* fp0 = &fw[(((size_t)rg * NBQ + 16 * kq + (lane >> 2)) * 4 + (lane & 3)) * 16];

  // ---- W into registers: 48 x bf16x8 = 192 VGPR ----
  bf16x8 wreg[12][4];
  {
    const int colbase = nb * 64;
    #pragma unroll
    for (int c = 0; c < 12; ++c)
      #pragma unroll
      for (int nt = 0; nt < 4; ++nt)
        wreg[c][nt] = *(const bf16x8*)(Wp
            + (size_t)(colbase + nt * 16 + l15) * KTOT
            + KMAP(kq, c) + lhi * 8);
  }

  // ---- bias folded into kq0's accumulator init (per-lane, per col-tile) ----
  float bv[4] = {0.f, 0.f, 0.f, 0.f};
  if (kq == 0) {
    #pragma unroll
    for (int nt = 0; nt < 4; ++nt) {
      int gc = nb * 64 + nt * 16 + l15;      // gate col (unit-major gc=unit*4+q)
      bv[nt] = bias[(gc & 3) * HID + (gc >> 2)];
    }
  }

  // ---- cell-update mapping: thread -> (row urow, units 2up,2up+1) ----
  const int urow = tid >> 3;                 // 0..31
  const int up   = tid & 7;
  const int rowg = rg * ROWS + urow;
  float cst[2] = {0.f, 0.f};

  // ---- prologue: x fragments for t=0 (chunks 0..3) ----
  bf16x8 af[2][12];
  #pragma unroll
  for (int c = 0; c < 4; ++c) {
    #pragma unroll
    for (int mt = 0; mt < 2; ++mt)
      af[mt][c] = *(const bf16x8*)(x + (size_t)(arow + mt * 16) * EMB
                                   + kq * 128 + c * 32 + lhi * 8);
  }

  #pragma unroll 1
  for (int t = 0; t < SEQ; ++t) {
    const int pb = t & 1;                    // pacc buffer for this step

    // ---- A: pre-poll x-part MFMAs (bias pre-loaded in kq0's acc) ----
    f32x4 acc[2][4];
    #pragma unroll
    for (int mt = 0; mt < 2; ++mt)
      #pragma unroll
      for (int nt = 0; nt < 4; ++nt)
        acc[mt][nt] = (f32x4){bv[nt], bv[nt], bv[nt], bv[nt]};
    #pragma unroll
    for (int c = 0; c < 4; ++c)
      #pragma unroll
      for (int mt = 0; mt < 2; ++mt)
        #pragma unroll
        for (int nt = 0; nt < 4; ++nt)
          acc[mt][nt] = mfma16(af[mt][c], wreg[c][nt], acc[mt][nt]);

    // ---- B: per-wave poll, 2 loads in flight (halved detect granularity) --
    if (t > 0) {
      const u32 tgt = (u32)t;
      int bail = 0;
      for (;;) {
        u32 a = __hip_atomic_load(fp0, __ATOMIC_RELAXED, __HIP_MEMORY_SCOPE_AGENT);
        u32 b = __hip_atomic_load(fp0, __ATOMIC_RELAXED, __HIP_MEMORY_SCOPE_AGENT);
        if (__all(a >= tgt)) break;
        if (__all(b >= tgt)) break;
        if (++bail > (1 << 21)) break;       // deadlock -> fast wrong-answer
      }
      __asm__ __volatile__("" ::: "memory");
    }

    // ---- C: h loads (plain cached; ring addr is never-stale) ----
    {
      const u16* hb = ring + (size_t)t * (BATCH * HID);
      #pragma unroll
      for (int c = 4; c < 12; ++c) {
        #pragma unroll
        for (int mt = 0; mt < 2; ++mt)
          af[mt][c] = *(const bf16x8*)(hb + (size_t)(arow + mt * 16) * HID
                                       + kq * 256 + (c - 4) * 32 + lhi * 8);
      }
    }

    // ---- E: h-part MFMAs (8 chunks, 64 MFMAs) ----
    #pragma unroll
    for (int c = 4; c < 12; ++c)
      #pragma unroll
      for (int mt = 0; mt < 2; ++mt)
        #pragma unroll
        for (int nt = 0; nt < 4; ++nt)
          acc[mt][nt] = mfma16(af[mt][c], wreg[c][nt], acc[mt][nt]);

    // ---- F: partials -> LDS buffer pb (XOR col swizzle) ----
    #pragma unroll
    for (int mt = 0; mt < 2; ++mt)
      #pragma unroll
      for (int nt = 0; nt < 4; ++nt)
        #pragma unroll
        for (int rr = 0; rr < 4; ++rr) {
          int row = mt * 16 + lhi * 4 + rr;
          int c   = nt * 16 + l15;
          int pc  = (c & ~7) | ((c ^ row) & 7);
          pacc[pb][kq][row][pc] = acc[mt][nt][rr];
        }
    __syncthreads();   // ONLY barrier: F-writes of buffer pb visible.

    // ---- G1: reduce over kq (bias arrives via kq0's partial) ----
    float s[2][4] = {{0.f, 0.f, 0.f, 0.f}, {0.f, 0.f, 0.f, 0.f}};
    #pragma unroll
    for (int k2 = 0; k2 < 4; ++k2)
      #pragma unroll
      for (int cl = 0; cl < 8; ++cl) {
        int pc = 8 * up + ((cl ^ urow) & 7);
        s[cl >> 2][cl & 3] += pacc[pb][k2][urow][pc];
      }

    // ---- G2: cell update + paired u64 store (sc0 sc1 WT, L3-alloc) ----
    {
      float hv2[2];
      #pragma unroll
      for (int k = 0; k < 2; ++k) {
        float cn = sigm(s[k][1]) * cst[k] + sigm(s[k][0]) * tanh_(s[k][2]);
        cst[k] = cn;
        hv2[k] = sigm(s[k][3]) * tanh_(cn);
      }
      u32 val = (u32)f2b(hv2[0]) | ((u32)f2b(hv2[1]) << 16);  // units 2up,2up+1
      u32 pv  = __shfl_xor(val, 1);                           // partner units
      if ((up & 1) == 0) {
        u64 v64 = ((u64)pv << 32) | (u64)val;                 // 4 units, 8B
        u64* dst = (u64*)(ring + (size_t)(t + 1) * (BATCH * HID)
                          + (size_t)rowg * HID + nb * 16 + 2 * up);
        asm volatile("global_store_dwordx2 %0, %1, off sc0 sc1"
                     :: "v"(dst), "v"(v64) : "memory");
      }
    }
    asm volatile("s_waitcnt vmcnt(0)" ::: "memory");  // drains the 128 h-stores

    // ---- H: fire-and-forget own flag (unconditional) ----
    if (lane == 0) {
      __hip_atomic_store(fw_own, (u32)(t + 1), __ATOMIC_RELAXED,
                         __HIP_MEMORY_SCOPE_AGENT);
    }

    // ---- D: x prefetch t+1 (after flag; covered by next step) ----
    if (t < SEQ - 1) {
      const u16* xb = x + (size_t)(t + 1) * (BATCH * EMB);
      #pragma unroll
      for (int c = 0; c < 4; ++c) {
        #pragma unroll
        for (int mt = 0; mt < 2; ++mt)
          af[mt][c] = *(const bf16x8*)(xb + (size_t)(arow + mt * 16) * EMB
                                       + kq * 128 + c * 32 + lhi * 8);
      }
    }
  }
}

// ---------------- classifier head: out = h_last @ W_out^T + b_out ----------
__global__ void head_kernel(const u16* __restrict__ h,
                            const float* __restrict__ Wout,
                            const float* __restrict__ bout,
                            float* __restrict__ out) {
  int b = blockIdx.x, l = threadIdx.x;
  float p[NOUT];
  #pragma unroll
  for (int o = 0; o < NOUT; ++o) p[o] = 0.f;
  for (int k = l; k < HID; k += 64) {
    float hv = b2f(h[(size_t)b * HID + k]);
    #pragma unroll
    for (int o = 0; o < NOUT; ++o) p[o] += hv * Wout[(size_t)o * HID + k];
  }
  #pragma unroll
  for (int o = 0; o < NOUT; ++o) {
    float v = p[o];
    #pragma unroll
    for (int off = 32; off > 0; off >>= 1) v += __shfl_down(v, off);
    if (l == 0) out[b * NOUT + o] = v + bout[o];
  }
}

// sentinel if workspace too small (distinguishable absmax ~1e9)
__global__ void sentinel_kernel(float* out, int n) {
  int i = blockIdx.x * 256 + threadIdx.x;
  if (i < n) out[i] = 1e9f;
}

extern "C" void kernel_launch(void* const* d_in, const int* in_sizes, int n_in,
                              void* d_out, int out_size, void* d_ws, size_t ws_size,
                              hipStream_t stream) {
  const int*   ids  = (const int*)d_in[0];
  const float* emb  = (const float*)d_in[1];
  const float* Wih  = (const float*)d_in[2];
  const float* Whh  = (const float*)d_in[3];
  const float* bias = (const float*)d_in[4];
  const float* Wout = (const float*)d_in[5];
  const float* bout = (const float*)d_in[6];
  float* out = (float*)d_out;

  if (ws_size < WS_NEED) {
    sentinel_kernel<<<(out_size + 255) / 256, 256, 0, stream>>>(out, out_size);
    return;
  }

  char* ws = (char*)d_ws;
  u16* x    = (u16*)(ws + OFF_X);
  u16* Wp   = (u16*)(ws + OFF_W);
  u16* ring = (u16*)(ws + OFF_RING);
  u32* fwv  = (u32*)(ws + OFF_FW);

  hipMemsetAsync(ring, 0, (size_t)BATCH * HID * 2, stream);  // ring[0] = h_0 = 0
  hipMemsetAsync(fwv, 0, SZ_FW, stream);                     // flags (every call!)

  embed_kernel<<<SEQ * BATCH, 128, 0, stream>>>(ids, emb, x);
  wpack_kernel<<<4 * HID, 256, 0, stream>>>(Wih, Whh, Wp);

  lstm_kernel<<<NBLK, 256, 0, stream>>>(x, Wp, bias, ring, fwv);

  head_kernel<<<BATCH, 64, 0, stream>>>(ring + (size_t)SEQ * BATCH * HID,
                                        Wout, bout, out);
}

// Round 24
// 2616.246 us; speedup vs baseline: 1.0088x; 1.0088x over previous
//
#include <hip/hip_runtime.h>
#include <cstdint>
#include <cstddef>

// ---------------- problem constants ----------------
#define SEQ    512
#define BATCH  128
#define EMB    512
#define HID    1024
#define KTOT   1536   // EMB + HID fused K
#define NOUT   8

// ---------------- decomposition ----------------
// 4 row-groups (32 batch rows) x 64 col-blocks (16 units / 64 gate-cols).
// Block = 256 thr = 4 waves; BALANCED K: every wave 4 x-chunks (pre-poll
// skew absorption) + 8 h-chunks (shorter post-poll path). W in VGPRs.
// Sync: per-WAVE monotone flags, sleep-free polls, 1 barrier/step.
// == R22, the best-measured variant (2622 us). Terminal submission. ==
#define RG     4
#define NBQ    64            // col-blocks per row-group
#define NBLK   (RG*NBQ)      // 256
#define ROWS   32            // batch rows per block

// balanced fused-K mapping for wave kq, chunk c (compile-time c)
#define KMAP(kq, c) ((c) < 4 ? ((kq)*128 + (c)*32) : (512 + (kq)*256 + ((c)-4)*32))

typedef unsigned short u16;
typedef unsigned int   u32;
typedef unsigned long long u64;
typedef __attribute__((ext_vector_type(8))) __bf16 bf16x8;
typedef __attribute__((ext_vector_type(4))) float  f32x4;
typedef __attribute__((ext_vector_type(4))) float  float4v;
typedef __attribute__((ext_vector_type(4))) u16    u16x4;

// ---------------- workspace layout ----------------
#define OFF_X    0ull
#define SZ_X     ((size_t)SEQ*BATCH*EMB*2)       // 64 MB  bf16 x [S][B][E]
#define OFF_W    (OFF_X + SZ_X)
#define SZ_W     ((size_t)4*HID*KTOT*2)          // 12 MB  bf16 Wp[gc][k], gc=unit*4+q
#define OFF_RING (OFF_W + SZ_W)
#define SZ_RING  ((size_t)(SEQ+1)*BATCH*HID*2)   // 134 MB h ring
#define OFF_FW   (OFF_RING + SZ_RING)
#define SZ_FW    ((size_t)RG*NBQ*4*64)           // 64 KB per-wave flag lines
#define WS_NEED  (OFF_FW + SZ_FW)

// ---------------- helpers ----------------
__device__ inline u16 f2b(float f) {            // f32 -> bf16 RNE
  uint32_t u = __builtin_bit_cast(uint32_t, f);
  u = u + 0x7FFFu + ((u >> 16) & 1u);
  return (u16)(u >> 16);
}
__device__ inline float b2f(u16 u) {
  uint32_t v = ((uint32_t)u) << 16;
  return __builtin_bit_cast(float, v);
}
__device__ inline float sigm(float x) { return 1.0f / (1.0f + __expf(-x)); }
__device__ inline float tanh_(float x) {
  x = fminf(fmaxf(x, -15.f), 15.f);
  float e = __expf(2.f * x);
  return (e - 1.f) / (e + 1.f);
}
__device__ inline f32x4 mfma16(bf16x8 a, bf16x8 b, f32x4 c) {
  return __builtin_amdgcn_mfma_f32_16x16x32_bf16(a, b, c, 0, 0, 0);
}

// ---------------- prep: embedding gather -> bf16 x[t][b][e] ----------------
__global__ void embed_kernel(const int* __restrict__ ids,
                             const float* __restrict__ emb,
                             u16* __restrict__ x) {
  int bid = blockIdx.x;            // t*128 + b
  int t = bid >> 7, b = bid & 127;
  int idx = ids[b * SEQ + t];
  const float4v* src = (const float4v*)(emb + (size_t)idx * EMB);
  float4v v = src[threadIdx.x];
  u16x4 o;
  o.x = f2b(v.x); o.y = f2b(v.y); o.z = f2b(v.z); o.w = f2b(v.w);
  *(u16x4*)(x + (size_t)bid * EMB + threadIdx.x * 4) = o;
}

// ---------------- prep: pack fused W, unit-major: gc=unit*4+q -----------
__global__ void wpack_kernel(const float* __restrict__ Wih,
                             const float* __restrict__ Whh,
                             u16* __restrict__ Wp) {
  int gc = blockIdx.x;             // 0..4095
  int unit = gc >> 2, q = gc & 3;
  int row = q * HID + unit;
  u16* dst = Wp + (size_t)gc * KTOT;
  for (int k = threadIdx.x; k < KTOT; k += 256) {
    float v = (k < EMB) ? Wih[(size_t)row * EMB + k]
                        : Whh[(size_t)row * HID + (k - EMB)];
    dst[k] = f2b(v);
  }
}

// ---------------- persistent LSTM recurrence (balanced, 1-barrier) ---------
__global__ __launch_bounds__(256, 1) void lstm_kernel(
    const u16* __restrict__ x,     // [SEQ][BATCH][EMB] bf16
    const u16* __restrict__ Wp,    // [4096][KTOT] bf16 packed
    const float* __restrict__ bias,// [4*HID] f32 gate-major
    u16* __restrict__ ring,        // [SEQ+1][BATCH][HID]; ring[0]=0
    u32* __restrict__ fw)          // [RG][NBQ][4] per-wave flags (zeroed; monotone)
{
  __shared__ float pacc[2][4][ROWS][68];     // double-buffered partials (70KB)

  const int tid  = threadIdx.x;
  const int bid  = blockIdx.x;
  const int rg   = bid & 3;        // row-group (co-XCD under round-robin)
  const int nb   = bid >> 2;       // col-block 0..63
  const int lane = tid & 63;
  const int kq   = tid >> 6;       // wave = balanced K-slice
  const int l15  = lane & 15;
  const int lhi  = lane >> 4;

  const int arow = rg * ROWS + l15;          // A-fragment base batch row

  // ---- producer flag line of THIS wave ----
  u32* fw_own = &fw[(((size_t)rg * NBQ + nb) * 4 + kq) * 16];
  // wave kq consumes h cols [kq*256, kq*256+256) -> producer blocks
  // cb in [16*kq, 16*kq+16): 64 flags, exactly one per lane.
  const u32* fp0 = &fw[(((size_t)rg * NBQ + 16 * kq + (lane >> 2)) * 4 + (lane & 3)) * 16];

  // ---- W into registers: 48 x bf16x8 = 192 VGPR ----
  bf16x8 wreg[12][4];
  {
    const int colbase = nb * 64;
    #pragma unroll
    for (int c = 0; c < 12; ++c)
      #pragma unroll
      for (int nt = 0; nt < 4; ++nt)
        wreg[c][nt] = *(const bf16x8*)(Wp
            + (size_t)(colbase + nt * 16 + l15) * KTOT
            + KMAP(kq, c) + lhi * 8);
  }

  // ---- cell-update mapping: thread -> (row urow, units 2up,2up+1) ----
  const int urow = tid >> 3;                 // 0..31
  const int up   = tid & 7;
  const int rowg = rg * ROWS + urow;
  float bs[2][4];
  #pragma unroll
  for (int k = 0; k < 2; ++k) {
    int ug = nb * 16 + 2 * up + k;
    #pragma unroll
    for (int q = 0; q < 4; ++q) bs[k][q] = bias[q * HID + ug];
  }
  float cst[2] = {0.f, 0.f};

  // ---- prologue: x fragments for t=0 (chunks 0..3) ----
  bf16x8 af[2][12];
  #pragma unroll
  for (int c = 0; c < 4; ++c) {
    #pragma unroll
    for (int mt = 0; mt < 2; ++mt)
      af[mt][c] = *(const bf16x8*)(x + (size_t)(arow + mt * 16) * EMB
                                   + kq * 128 + c * 32 + lhi * 8);
  }

  #pragma unroll 1
  for (int t = 0; t < SEQ; ++t) {
    const int pb = t & 1;                    // pacc buffer for this step

    // ---- A: pre-poll x-part MFMAs (every wave: 32 MFMAs of skew cover) ----
    f32x4 acc[2][4];
    #pragma unroll
    for (int mt = 0; mt < 2; ++mt)
      #pragma unroll
      for (int nt = 0; nt < 4; ++nt) acc[mt][nt] = (f32x4){0.f, 0.f, 0.f, 0.f};
    #pragma unroll
    for (int c = 0; c < 4; ++c)
      #pragma unroll
      for (int mt = 0; mt < 2; ++mt)
        #pragma unroll
        for (int nt = 0; nt < 4; ++nt)
          acc[mt][nt] = mfma16(af[mt][c], wreg[c][nt], acc[mt][nt]);

    // ---- B: per-wave poll, one flag per lane (sleep-free) ----
    if (t > 0) {
      const u32 tgt = (u32)t;
      int bail = 0;
      for (;;) {
        u32 a = __hip_atomic_load(fp0, __ATOMIC_RELAXED, __HIP_MEMORY_SCOPE_AGENT);
        if (__all(a >= tgt)) break;
        if (++bail > (1 << 22)) break;       // deadlock -> fast wrong-answer
      }
      __asm__ __volatile__("" ::: "memory");
    }

    // ---- C: h loads (plain cached; ring addr is never-stale) ----
    {
      const u16* hb = ring + (size_t)t * (BATCH * HID);
      #pragma unroll
      for (int c = 4; c < 12; ++c) {
        #pragma unroll
        for (int mt = 0; mt < 2; ++mt)
          af[mt][c] = *(const bf16x8*)(hb + (size_t)(arow + mt * 16) * HID
                                       + kq * 256 + (c - 4) * 32 + lhi * 8);
      }
    }

    // ---- E: h-part MFMAs (8 chunks, 64 MFMAs) ----
    #pragma unroll
    for (int c = 4; c < 12; ++c)
      #pragma unroll
      for (int mt = 0; mt < 2; ++mt)
        #pragma unroll
        for (int nt = 0; nt < 4; ++nt)
          acc[mt][nt] = mfma16(af[mt][c], wreg[c][nt], acc[mt][nt]);

    // ---- F: partials -> LDS buffer pb (XOR col swizzle) ----
    #pragma unroll
    for (int mt = 0; mt < 2; ++mt)
      #pragma unroll
      for (int nt = 0; nt < 4; ++nt)
        #pragma unroll
        for (int rr = 0; rr < 4; ++rr) {
          int row = mt * 16 + lhi * 4 + rr;
          int c   = nt * 16 + l15;
          int pc  = (c & ~7) | ((c ^ row) & 7);
          pacc[pb][kq][row][pc] = acc[mt][nt][rr];
        }
    __syncthreads();   // ONLY barrier: F-writes of buffer pb visible.

    // ---- G1: reduce over kq (reads buffer pb) ----
    float s[2][4];
    #pragma unroll
    for (int k = 0; k < 2; ++k)
      #pragma unroll
      for (int q = 0; q < 4; ++q) s[k][q] = bs[k][q];
    #pragma unroll
    for (int k2 = 0; k2 < 4; ++k2)
      #pragma unroll
      for (int cl = 0; cl < 8; ++cl) {
        int pc = 8 * up + ((cl ^ urow) & 7);
        s[cl >> 2][cl & 3] += pacc[pb][k2][urow][pc];
      }

    // ---- G2: cell update + packed store (sc0 sc1 WT, L3-alloc) ----
    {
      float hv2[2];
      #pragma unroll
      for (int k = 0; k < 2; ++k) {
        float cn = sigm(s[k][1]) * cst[k] + sigm(s[k][0]) * tanh_(s[k][2]);
        cst[k] = cn;
        hv2[k] = sigm(s[k][3]) * tanh_(cn);
      }
      u32 val = (u32)f2b(hv2[0]) | ((u32)f2b(hv2[1]) << 16);
      u32* dst = (u32*)(ring + (size_t)(t + 1) * (BATCH * HID)
                        + (size_t)rowg * HID + nb * 16 + 2 * up);
      asm volatile("global_store_dword %0, %1, off sc0 sc1"
                   :: "v"(dst), "v"(val) : "memory");
    }
    asm volatile("s_waitcnt vmcnt(0)" ::: "memory");  // drains ONLY the h-store

    // ---- H: fire-and-forget own flag ----
    if (t < SEQ - 1 && lane == 0) {
      __hip_atomic_store(fw_own, (u32)(t + 1), __ATOMIC_RELAXED,
                         __HIP_MEMORY_SCOPE_AGENT);
    }

    // ---- D: x prefetch t+1 (after flag; covered by next step) ----
    if (t < SEQ - 1) {
      const u16* xb = x + (size_t)(t + 1) * (BATCH * EMB);
      #pragma unroll
      for (int c = 0; c < 4; ++c) {
        #pragma unroll
        for (int mt = 0; mt < 2; ++mt)
          af[mt][c] = *(const bf16x8*)(xb + (size_t)(arow + mt * 16) * EMB
                                       + kq * 128 + c * 32 + lhi * 8);
      }
    }
  }
}

// ---------------- classifier head: out = h_last @ W_out^T + b_out ----------
__global__ void head_kernel(const u16* __restrict__ h,
                            const float* __restrict__ Wout,
                            const float* __restrict__ bout,
                            float* __restrict__ out) {
  int b = blockIdx.x, l = threadIdx.x;
  float p[NOUT];
  #pragma unroll
  for (int o = 0; o < NOUT; ++o) p[o] = 0.f;
  for (int k = l; k < HID; k += 64) {
    float hv = b2f(h[(size_t)b * HID + k]);
    #pragma unroll
    for (int o = 0; o < NOUT; ++o) p[o] += hv * Wout[(size_t)o * HID + k];
  }
  #pragma unroll
  for (int o = 0; o < NOUT; ++o) {
    float v = p[o];
    #pragma unroll
    for (int off = 32; off > 0; off >>= 1) v += __shfl_down(v, off);
    if (l == 0) out[b * NOUT + o] = v + bout[o];
  }
}

// sentinel if workspace too small (distinguishable absmax ~1e9)
__global__ void sentinel_kernel(float* out, int n) {
  int i = blockIdx.x * 256 + threadIdx.x;
  if (i < n) out[i] = 1e9f;
}

extern "C" void kernel_launch(void* const* d_in, const int* in_sizes, int n_in,
                              void* d_out, int out_size, void* d_ws, size_t ws_size,
                              hipStream_t stream) {
  const int*   ids  = (const int*)d_in[0];
  const float* emb  = (const float*)d_in[1];
  const float* Wih  = (const float*)d_in[2];
  const float* Whh  = (const float*)d_in[3];
  const float* bias = (const float*)d_in[4];
  const float* Wout = (const float*)d_in[5];
  const float* bout = (const float*)d_in[6];
  float* out = (float*)d_out;

  if (ws_size < WS_NEED) {
    sentinel_kernel<<<(out_size + 255) / 256, 256, 0, stream>>>(out, out_size);
    return;
  }

  char* ws = (char*)d_ws;
  u16* x    = (u16*)(ws + OFF_X);
  u16* Wp   = (u16*)(ws + OFF_W);
  u16* ring = (u16*)(ws + OFF_RING);
  u32* fwv  = (u32*)(ws + OFF_FW);

  hipMemsetAsync(ring, 0, (size_t)BATCH * HID * 2, stream);  // ring[0] = h_0 = 0
  hipMemsetAsync(fwv, 0, SZ_FW, stream);                     // flags (every call!)

  embed_kernel<<<SEQ * BATCH, 128, 0, stream>>>(ids, emb, x);
  wpack_kernel<<<4 * HID, 256, 0, stream>>>(Wih, Whh, Wp);

  lstm_kernel<<<NBLK, 256, 0, stream>>>(x, Wp, bias, ring, fwv);

  head_kernel<<<BATCH, 64, 0, stream>>>(ring + (size_t)SEQ * BATCH * HID,
                                        Wout, bout, out);
}